// Round 12
// baseline (396.436 us; speedup 1.0000x reference)
//
#include <hip/hip_runtime.h>

#define T_STEPS 256
#define FEAT 16
#define U1 24
#define U2 48
#define BATCH_PB 8    // batches per block: half-filled MFMA columns -> 2 waves/SIMD
#define SLOTS 8       // ring: 2 macro-steps x 4

typedef short bf16x8 __attribute__((ext_vector_type(8)));
typedef float f32x4 __attribute__((ext_vector_type(4)));

__device__ __forceinline__ unsigned short f2bf(float f) {
    unsigned u = __float_as_uint(f);
    u += 0x7fffu + ((u >> 16) & 1u);   // RNE
    return (unsigned short)(u >> 16);
}

#if defined(__has_builtin)
#if __has_builtin(__builtin_amdgcn_cvt_pk_bf16_f32)
#define HAVE_PKBF16 1
#endif
#if __has_builtin(__builtin_amdgcn_rcpf)
#define HAVE_RCP 1
#endif
#if __has_builtin(__builtin_amdgcn_rsqf)
#define HAVE_RSQ 1
#endif
#if __has_builtin(__builtin_amdgcn_exp2f)
#define HAVE_EXP2 1
#endif
#endif

__device__ __forceinline__ unsigned pk2(float a, float b) {
#ifdef HAVE_PKBF16
    typedef __bf16 bf2 __attribute__((ext_vector_type(2)));
    union { bf2 v; unsigned u; } cv;
    cv.v = __builtin_amdgcn_cvt_pk_bf16_f32(a, b);   // lo = a, hi = b, RNE
    return cv.u;
#else
    return (unsigned)f2bf(a) | ((unsigned)f2bf(b) << 16);
#endif
}
__device__ __forceinline__ float bfr(float x) {      // round f32 -> bf16 -> f32
    return __uint_as_float(((unsigned)f2bf(x)) << 16);
}

// HW-TRANS math: avoid IEEE div/sqrt expansions (~10 VALU each).
// rel err ~1e-6 << bf16 rounding (4e-3) in the data path.
__device__ __forceinline__ float hrcp(float x) {
#ifdef HAVE_RCP
    return __builtin_amdgcn_rcpf(x);
#else
    return 1.0f / x;
#endif
}
__device__ __forceinline__ float hrsq(float x) {
#ifdef HAVE_RSQ
    return __builtin_amdgcn_rsqf(x);
#else
    return rsqrtf(x);
#endif
}
__device__ __forceinline__ float hexp2(float x) {
#ifdef HAVE_EXP2
    return __builtin_amdgcn_exp2f(x);
#else
    return exp2f(x);
#endif
}
__device__ __forceinline__ float fast_tanh(float z) {
    // 1 - 2/(1+e^{2z}) = fma(-2, rcp(1+exp2(2*log2e*z)), 1); robust at +/-inf
    const float e = hexp2(z * 2.8853900817779268f);
    return fmaf(-2.0f, hrcp(1.0f + e), 1.0f);
}

union FragU { bf16x8 v; unsigned u[4]; };

#define MFMA(A, B, C) __builtin_amdgcn_mfma_f32_16x16x32_bf16((A), (B), (C), 0, 0, 0)

// lgkm-only barrier (0xC07F = vmcnt(63) expcnt(7) lgkmcnt(0)):
// input-prefetch global loads stay in flight across the barrier.
__device__ __forceinline__ void bar_sync() {
    asm volatile("" ::: "memory");
    __builtin_amdgcn_s_waitcnt(0xC07F);
    __builtin_amdgcn_s_barrier();
    asm volatile("" ::: "memory");
}

// D-layout (col=lane&15,row=4g+r) and B-layout (n=lane&15,k=8g+j) share the
// batch->lane mapping, so D->B needs NO data movement: pack D regs into the
// B-frag dwords and permute the A-operand rows instead. Formal slot k=8g+j
// holds unit u(k) = (j<4 ? 4g+j : 16+4g+(j-4)). Ring handoff is lane-aligned.
//
// TLP (round 12): BATCH_PB=8 half-fills the MFMA's 16 columns (cols 8-15
// compute zeros, never stored) -> 1024 blocks x 2 waves = 2 waves/SIMD.
// Each wave's stalls (~40-50% of wall at 1 wave/SIMD) overlap the co-resident
// wave's issue. MFMA issue doubles from 7% util (affordable); VALU total
// issue unchanged. Body kept byte-identical to the verified 160-VGPR optimum
// (rounds 5-10: any body perturbation collapsed the allocator to 96-136 VGPRs
// and regressed). Tripwire: VGPR_Count must stay ~160.

__global__ __launch_bounds__(128) void rnn_kernel(
    const float* __restrict__ seq,
    const float* __restrict__ W1, const float* __restrict__ b1,
    const float* __restrict__ Wr1, const float* __restrict__ br1,
    const float* __restrict__ g1, const float* __restrict__ be1,
    const float* __restrict__ W2, const float* __restrict__ b2,
    const float* __restrict__ Wr2, const float* __restrict__ br2,
    const float* __restrict__ g2, const float* __restrict__ be2,
    const float* __restrict__ Wout, const float* __restrict__ bout,
    float* __restrict__ out)
{
    // ring: packed bf16 B-frags, 16 B/lane stride -> conflict-free b128 both sides
    __shared__ __align__(16) unsigned ringN[SLOTS][64][4];   // n1   frags, 8 KiB
    __shared__ __align__(16) unsigned ringQ[SLOTS][64][4];   // n1^2 frags, 8 KiB

    const int tid = threadIdx.x;
    const int w = tid >> 6;              // 0 = layer-1 producer, 1 = layer-2 consumer
    const int lane = tid & 63;
    const int j15 = lane & 15;
    const int g = lane >> 4;
    const f32x4 z4 = {0.f, 0.f, 0.f, 0.f};

    if (w == 0) {
        // ================= PRODUCER: layer 1 (s1 chain) =================
        bf16x8 A1[2], A2[2];
#pragma unroll
        for (int t = 0; t < 2; ++t) {
            const int m = 16 * t + j15;
            FragU f1, f2;
#pragma unroll
            for (int j = 0; j < 8; ++j) {
                const int k = 8 * g + j;                       // natural k (A1: input feats)
                const int u = (j < 4) ? 4 * g + j : 16 + 4 * g + (j - 4);  // relabeled unit
                float v1 = 0.f, v2 = 0.f;
                if (m < U1) {
                    if (k < FEAT) v1 = W1[k * U1 + m];
                    else if (k == FEAT) v1 = b1[m];            // bias col (input k16 == 1)
                    if (u < U1) v2 = Wr1[u * U1 + m];
                    else if (u == U1) v2 = br1[m];             // bias col (x24 == 1)
                } else if (m == U1 && k == FEAT) {
                    v1 = 1.f;                                  // keeps x24 = 1 each step
                }
                f1.v[j] = (short)f2bf(v1);
                f2.v[j] = (short)f2bf(v2);
            }
            A1[t] = f1.v; A2[t] = f2.v;
        }
        const unsigned cdw0 = (g == 2) ? 0x00003F80u : 0u;     // input k16 = 1.0

        const float* sp = seq + (size_t)(blockIdx.x * BATCH_PB + j15) * (T_STEPS * FEAT) + 8 * g;
        const bool ld = (lane < 32) && (j15 < BATCH_PB);       // cols >= BATCH_PB are dead

        f32x4 s1[2] = {z4, z4};

        auto pstep = [&](int t, const float4 ca, const float4 cb) {
            FragU inf;
            const unsigned p0 = pk2(ca.x, ca.y), p1 = pk2(ca.z, ca.w);
            const unsigned p2 = pk2(cb.x, cb.y), p3 = pk2(cb.z, cb.w);
            const bool lo = (g < 2);
            inf.u[0] = lo ? p0 : cdw0;
            inf.u[1] = lo ? p1 : 0u;
            inf.u[2] = lo ? p2 : 0u;
            inf.u[3] = lo ? p3 : 0u;

            // GEMM1: x^T = [W1^T|b1].in^T + s1
            const f32x4 x0 = MFMA(A1[0], inf.v, s1[0]);
            const f32x4 x1 = MFMA(A1[1], inf.v, s1[1]);

            // D->B in-register: own D regs ARE the B-frag under relabeled A2
            FragU xf;
            xf.u[0] = pk2(x0[0], x0[1]); xf.u[1] = pk2(x0[2], x0[3]);
            xf.u[2] = pk2(x1[0], x1[1]); xf.u[3] = pk2(x1[2], x1[3]);

            // GEMM2: ns1 = tanh([Wr1^T|br1].x^T)
            const f32x4 d0 = MFMA(A2[0], xf.v, z4);
            const f32x4 d1 = MFMA(A2[1], xf.v, z4);
            float n1a[4], n1b[4], qa[4], qb[4];
#pragma unroll
            for (int r = 0; r < 4; ++r) {
                n1a[r] = fast_tanh(d0[r]); n1b[r] = fast_tanh(d1[r]);
                qa[r] = n1a[r] * n1a[r];   qb[r] = n1b[r] * n1b[r];
                s1[0][r] = n1a[r];         s1[1][r] = n1b[r];
            }
            // handoff: lane-aligned packed B-frags (no transpose needed)
            FragU nf, qf;
            nf.u[0] = pk2(n1a[0], n1a[1]); nf.u[1] = pk2(n1a[2], n1a[3]);
            nf.u[2] = pk2(n1b[0], n1b[1]); nf.u[3] = pk2(n1b[2], n1b[3]);
            qf.u[0] = pk2(qa[0], qa[1]);   qf.u[1] = pk2(qa[2], qa[3]);
            qf.u[2] = pk2(qb[0], qb[1]);   qf.u[3] = pk2(qb[2], qb[3]);
            const int slot = t & (SLOTS - 1);
            *(uint4*)&ringN[slot][lane][0] = make_uint4(nf.u[0], nf.u[1], nf.u[2], nf.u[3]);
            *(uint4*)&ringQ[slot][lane][0] = make_uint4(qf.u[0], qf.u[1], qf.u[2], qf.u[3]);
        };

        // load macro 0 (zero-init: dead-column lanes keep exact zeros forever)
        float4 ca[4] = {}, cb[4] = {}, na[4] = {}, nb[4] = {};
        if (ld) {
#pragma unroll
            for (int i = 0; i < 4; ++i) {
                ca[i] = *(const float4*)(sp + i * 16);
                cb[i] = *(const float4*)(sp + i * 16 + 4);
            }
        }
#pragma unroll 1
        for (int j = 0; j < 64; ++j) {
            const int jn = (j + 1 < 64) ? j + 1 : j;     // prefetch next macro
            if (ld) {
#pragma unroll
                for (int i = 0; i < 4; ++i) {
                    na[i] = *(const float4*)(sp + (4 * jn + i) * 16);
                    nb[i] = *(const float4*)(sp + (4 * jn + i) * 16 + 4);
                }
            }
#pragma unroll
            for (int i = 0; i < 4; ++i) pstep(4 * j + i, ca[i], cb[i]);
            bar_sync();                                   // 64 in-loop barriers
#pragma unroll
            for (int i = 0; i < 4; ++i) { ca[i] = na[i]; cb[i] = nb[i]; }
        }
        bar_sync();                                       // barrier #65
    } else {
        // ================= CONSUMER: layer 2 (s2 chain) =================
        // A3a[t<3] = gamma-folded W2^T (relabeled rows); A3a[3]/A3b3 = sum tiles.
        bf16x8 A3a[4], A3b3, A4[3][2];
#pragma unroll
        for (int t = 0; t < 3; ++t) {
            const int m = 16 * t + j15;
            FragU f3, f4a, f4b;
#pragma unroll
            for (int j = 0; j < 8; ++j) {
                const int u = (j < 4) ? 4 * g + j : 16 + 4 * g + (j - 4);  // relabeled unit
                f3.v[j] = (short)f2bf(u < U1 ? g1[u] * W2[u * U2 + m] : 0.f);
                f4a.v[j] = (short)f2bf(Wr2[u * U2 + m]);               // y-units 0..31
                float vb = 0.f;
                if (j < 4) vb = Wr2[(32 + 4 * g + j) * U2 + m];        // y-units 32..47
                else if (j == 4 && g == 0) vb = br2[m];                // bias at formal k=4
                f4b.v[j] = (short)f2bf(vb);
            }
            A3a[t] = f3.v; A4[t][0] = f4a.v; A4[t][1] = f4b.v;
        }
        {   // sum tiles: rows m%4==0 -> ones over n1 units; rows m%4==1 -> over n1^2
            FragU fa, fb;
#pragma unroll
            for (int j = 0; j < 8; ++j) {
                const int u = (j < 4) ? 4 * g + j : 16 + 4 * g + (j - 4);
                fa.v[j] = ((j15 & 3) == 0 && u < U1) ? (short)0x3F80 : (short)0;
                fb.v[j] = ((j15 & 3) == 1 && u < U1) ? (short)0x3F80 : (short)0;
            }
            A3a[3] = fa.v; A3b3 = fb.v;
        }
        // per-lane LN-fold constants: c[m] = sum_k bf16(g1.W2), d[m] = b2 + W2^T.be1
        float cC[12], dC[12];
#pragma unroll
        for (int i = 0; i < 12; ++i) {
            const int m = 16 * (i >> 2) + 4 * g + (i & 3);
            float cc = 0.f, dd = b2[m];
            for (int k = 0; k < U1; ++k) {
                const float wq = bfr(g1[k] * W2[k * U2 + m]);   // match matmul quantization
                cc += wq;
                dd += be1[k] * W2[k * U2 + m];
            }
            cC[i] = cc; dC[i] = dd;
        }
        f32x4 s2[3] = {z4, z4, z4};

        auto cstep = [&](int t) {
            const int slot = t & (SLOTS - 1);
            const bf16x8 hf0 = *(const bf16x8*)&ringN[slot][lane][0];  // n1 frag
            const bf16x8 hf1 = *(const bf16x8*)&ringQ[slot][lane][0];  // n1^2 frag

            // sums first (gates rs), then P tiles — all off the s2 recurrence
            f32x4 sAcc = MFMA(A3a[3], hf0, z4);
            sAcc = MFMA(A3b3, hf1, sAcc);                 // reg0 = Sum n1, reg1 = Sum n1^2
            const f32x4 P0 = MFMA(A3a[0], hf0, z4);
            const f32x4 P1 = MFMA(A3a[1], hf0, z4);
            const f32x4 P2 = MFMA(A3a[2], hf0, z4);

            const float mu = sAcc[0] * (1.f / U1);
            const float var = sAcc[1] * (1.f / U1) - mu * mu;
            const float rs = hrsq(var + 1e-3f);

            // y = rs*(P - mu*c) + (d + s2)
            float y[12];
#pragma unroll
            for (int r = 0; r < 4; ++r) {
                y[r]     = fmaf(rs, fmaf(-mu, cC[r],     P0[r]), dC[r]     + s2[0][r]);
                y[4 + r] = fmaf(rs, fmaf(-mu, cC[4 + r], P1[r]), dC[4 + r] + s2[1][r]);
                y[8 + r] = fmaf(rs, fmaf(-mu, cC[8 + r], P2[r]), dC[8 + r] + s2[2][r]);
            }

            // y as B-frags in-register; bias 1.0 at formal (g==0, j==4) of yf1
            FragU yf0, yf1;
            yf0.u[0] = pk2(y[0], y[1]);  yf0.u[1] = pk2(y[2], y[3]);
            yf0.u[2] = pk2(y[4], y[5]);  yf0.u[3] = pk2(y[6], y[7]);
            yf1.u[0] = pk2(y[8], y[9]);  yf1.u[1] = pk2(y[10], y[11]);
            yf1.u[2] = (g == 0) ? 0x00003F80u : 0u;
            yf1.u[3] = 0u;

            // GEMM4: s2 = tanh([Wr2^T|br2].y^T)
#pragma unroll
            for (int t3 = 0; t3 < 3; ++t3) {
                f32x4 e = MFMA(A4[t3][0], yf0.v, z4);
                e = MFMA(A4[t3][1], yf1.v, e);
#pragma unroll
                for (int r = 0; r < 4; ++r) s2[t3][r] = fast_tanh(e[r]);
            }
        };

        bar_sync();                                       // wait for producer macro 0
#pragma unroll 1
        for (int j = 0; j < 64; ++j) {
#pragma unroll
            for (int i = 0; i < 4; ++i) cstep(4 * j + i);
            bar_sync();                                   // 64 in-loop barriers
        }

        // ---- epilogue: out = sigmoid(LN(s2) @ Wout + bout) ----
        float g2r[12], be2r[12], wor[12];
#pragma unroll
        for (int r = 0; r < 12; ++r) {
            const int n = 16 * (r >> 2) + 4 * g + (r & 3);
            g2r[r] = g2[n]; be2r[r] = be2[n]; wor[r] = Wout[n];
        }
        float sm = 0.f, sq = 0.f;
#pragma unroll
        for (int tt = 0; tt < 3; ++tt)
#pragma unroll
            for (int r = 0; r < 4; ++r) { const float v = s2[tt][r]; sm += v; sq += v * v; }
        sm += __shfl_xor(sm, 16, 64); sq += __shfl_xor(sq, 16, 64);
        sm += __shfl_xor(sm, 32, 64); sq += __shfl_xor(sq, 32, 64);
        const float mu = sm * (1.f / U2);
        const float var = sq * (1.f / U2) - mu * mu;
        const float rs = hrsq(var + 1e-3f);
        float p = 0.f;
#pragma unroll
        for (int tt = 0; tt < 3; ++tt)
#pragma unroll
            for (int r = 0; r < 4; ++r)
                p += ((s2[tt][r] - mu) * rs * g2r[4 * tt + r] + be2r[4 * tt + r]) * wor[4 * tt + r];
        p += __shfl_xor(p, 16, 64);
        p += __shfl_xor(p, 32, 64);
        if (lane < BATCH_PB) {
            const float z = p + bout[0];
            // sigmoid via exp2 + HW rcp (once per output; keep cheap anyway)
            const float e = hexp2(-z * 1.4426950408889634f);
            out[blockIdx.x * BATCH_PB + lane] = hrcp(1.0f + e);
        }
    }
}

extern "C" void kernel_launch(void* const* d_in, const int* in_sizes, int n_in,
                              void* d_out, int out_size, void* d_ws, size_t ws_size,
                              hipStream_t stream) {
    const float* seq  = (const float*)d_in[0];
    const float* W1   = (const float*)d_in[1];
    const float* b1   = (const float*)d_in[2];
    const float* Wr1  = (const float*)d_in[3];
    const float* br1  = (const float*)d_in[4];
    const float* g1   = (const float*)d_in[5];
    const float* be1  = (const float*)d_in[6];
    const float* W2   = (const float*)d_in[7];
    const float* b2   = (const float*)d_in[8];
    const float* Wr2  = (const float*)d_in[9];
    const float* br2  = (const float*)d_in[10];
    const float* g2   = (const float*)d_in[11];
    const float* be2  = (const float*)d_in[12];
    const float* Wout = (const float*)d_in[13];
    const float* bout = (const float*)d_in[14];
    float* out = (float*)d_out;

    const int B = in_sizes[0] / (T_STEPS * FEAT);   // 8192
    const int grid = B / BATCH_PB;                  // 1024 blocks x 2 waves = 2 waves/SIMD
    rnn_kernel<<<grid, 128, 0, stream>>>(seq, W1, b1, Wr1, br1, g1, be1,
                                         W2, b2, Wr2, br2, g2, be2, Wout, bout, out);
}

// Round 13
// 285.764 us; speedup vs baseline: 1.3873x; 1.3873x over previous
//
#include <hip/hip_runtime.h>

#define T_STEPS 256
#define FEAT 16
#define U1 24
#define U2 48
#define SLOTS 8       // ring: 2 macro-steps x 4

typedef short bf16x8 __attribute__((ext_vector_type(8)));
typedef float f32x4 __attribute__((ext_vector_type(4)));

__device__ __forceinline__ unsigned short f2bf(float f) {
    unsigned u = __float_as_uint(f);
    u += 0x7fffu + ((u >> 16) & 1u);   // RNE
    return (unsigned short)(u >> 16);
}

#if defined(__has_builtin)
#if __has_builtin(__builtin_amdgcn_cvt_pk_bf16_f32)
#define HAVE_PKBF16 1
#endif
#if __has_builtin(__builtin_amdgcn_rcpf)
#define HAVE_RCP 1
#endif
#if __has_builtin(__builtin_amdgcn_rsqf)
#define HAVE_RSQ 1
#endif
#if __has_builtin(__builtin_amdgcn_exp2f)
#define HAVE_EXP2 1
#endif
#endif

__device__ __forceinline__ unsigned pk2(float a, float b) {
#ifdef HAVE_PKBF16
    typedef __bf16 bf2 __attribute__((ext_vector_type(2)));
    union { bf2 v; unsigned u; } cv;
    cv.v = __builtin_amdgcn_cvt_pk_bf16_f32(a, b);   // lo = a, hi = b, RNE
    return cv.u;
#else
    return (unsigned)f2bf(a) | ((unsigned)f2bf(b) << 16);
#endif
}
__device__ __forceinline__ float bfr(float x) {      // round f32 -> bf16 -> f32
    return __uint_as_float(((unsigned)f2bf(x)) << 16);
}

// HW-TRANS math: avoid IEEE div/sqrt expansions (~10 VALU each).
// rel err ~1e-6 << bf16 rounding (4e-3) in the data path.
__device__ __forceinline__ float hrcp(float x) {
#ifdef HAVE_RCP
    return __builtin_amdgcn_rcpf(x);
#else
    return 1.0f / x;
#endif
}
__device__ __forceinline__ float hrsq(float x) {
#ifdef HAVE_RSQ
    return __builtin_amdgcn_rsqf(x);
#else
    return rsqrtf(x);
#endif
}
__device__ __forceinline__ float hexp2(float x) {
#ifdef HAVE_EXP2
    return __builtin_amdgcn_exp2f(x);
#else
    return exp2f(x);
#endif
}
__device__ __forceinline__ float fast_tanh(float z) {
    // 1 - 2/(1+e^{2z}) = fma(-2, rcp(1+exp2(2*log2e*z)), 1); robust at +/-inf
    const float e = hexp2(z * 2.8853900817779268f);
    return fmaf(-2.0f, hrcp(1.0f + e), 1.0f);
}

union FragU { bf16x8 v; unsigned u[4]; };

#define MFMA(A, B, C) __builtin_amdgcn_mfma_f32_16x16x32_bf16((A), (B), (C), 0, 0, 0)

// lgkm-only barrier (0xC07F = vmcnt(63) expcnt(7) lgkmcnt(0)):
// input-prefetch global loads stay in flight across the barrier.
__device__ __forceinline__ void bar_sync() {
    asm volatile("" ::: "memory");
    __builtin_amdgcn_s_waitcnt(0xC07F);
    __builtin_amdgcn_s_barrier();
    asm volatile("" ::: "memory");
}

// D-layout (col=lane&15,row=4g+r) and B-layout (n=lane&15,k=8g+j) share the
// batch->lane mapping, so D->B needs NO data movement: pack D regs into the
// B-frag dwords and permute the A-operand rows instead. Formal slot k=8g+j
// holds unit u(k) = (j<4 ? 4g+j : 16+4g+(j-4)). Ring handoff is lane-aligned:
// producer lane (j15,g) packs exactly the rows consumer lane (j15,g) needs.
//
// FINAL STATE (12-round session). Verified best: 286.8/288.4 us harness
// (two runs, same source). This body is a sharply peaked codegen optimum:
// the allocator picks 160 VGPRs and keeps the producer's 16-float4 prefetch
// live across barriers. Falsified alternatives (all measured):
//  - move LN sums / P-tiles to producer ....... 227-309 us (chain rebalance)
//  - fused single-wave (no LDS/barriers) ...... 288 us (serialized chains)
//  - 8-step barrier periods (33 barriers) ..... 213 us (codegen collapse, 136 VGPR)
//  - lighter consumer (no ringQ, reg sums) .... 229 us (96-VGPR collapse)
//  - __launch_bounds__(128,1) hint ............ 269 us (allocator ignores)
//  - BATCH_PB=8 for 2 waves/SIMD .............. 396 us (duplicates VALU work)
// Wins kept: in-register D->B relabel (no LDS transposes, 0 bank conflicts),
// HW-TRANS math (exp2+rcp tanh, rsq LN), LN folded into A3/c/d constants.
// Do not perturb the body without re-checking VGPR_Count == 160.

__global__ __launch_bounds__(128) void rnn_kernel(
    const float* __restrict__ seq,
    const float* __restrict__ W1, const float* __restrict__ b1,
    const float* __restrict__ Wr1, const float* __restrict__ br1,
    const float* __restrict__ g1, const float* __restrict__ be1,
    const float* __restrict__ W2, const float* __restrict__ b2,
    const float* __restrict__ Wr2, const float* __restrict__ br2,
    const float* __restrict__ g2, const float* __restrict__ be2,
    const float* __restrict__ Wout, const float* __restrict__ bout,
    float* __restrict__ out)
{
    // ring: packed bf16 B-frags, 16 B/lane stride -> conflict-free b128 both sides
    __shared__ __align__(16) unsigned ringN[SLOTS][64][4];   // n1   frags, 8 KiB
    __shared__ __align__(16) unsigned ringQ[SLOTS][64][4];   // n1^2 frags, 8 KiB

    const int tid = threadIdx.x;
    const int w = tid >> 6;              // 0 = layer-1 producer, 1 = layer-2 consumer
    const int lane = tid & 63;
    const int j15 = lane & 15;
    const int g = lane >> 4;
    const f32x4 z4 = {0.f, 0.f, 0.f, 0.f};

    if (w == 0) {
        // ================= PRODUCER: layer 1 (s1 chain) =================
        bf16x8 A1[2], A2[2];
#pragma unroll
        for (int t = 0; t < 2; ++t) {
            const int m = 16 * t + j15;
            FragU f1, f2;
#pragma unroll
            for (int j = 0; j < 8; ++j) {
                const int k = 8 * g + j;                       // natural k (A1: input feats)
                const int u = (j < 4) ? 4 * g + j : 16 + 4 * g + (j - 4);  // relabeled unit
                float v1 = 0.f, v2 = 0.f;
                if (m < U1) {
                    if (k < FEAT) v1 = W1[k * U1 + m];
                    else if (k == FEAT) v1 = b1[m];            // bias col (input k16 == 1)
                    if (u < U1) v2 = Wr1[u * U1 + m];
                    else if (u == U1) v2 = br1[m];             // bias col (x24 == 1)
                } else if (m == U1 && k == FEAT) {
                    v1 = 1.f;                                  // keeps x24 = 1 each step
                }
                f1.v[j] = (short)f2bf(v1);
                f2.v[j] = (short)f2bf(v2);
            }
            A1[t] = f1.v; A2[t] = f2.v;
        }
        const unsigned cdw0 = (g == 2) ? 0x00003F80u : 0u;     // input k16 = 1.0

        const float* sp = seq + (size_t)(blockIdx.x * 16 + j15) * (T_STEPS * FEAT) + 8 * g;
        const bool ld = (lane < 32);

        f32x4 s1[2] = {z4, z4};

        auto pstep = [&](int t, const float4 ca, const float4 cb) {
            FragU inf;
            const unsigned p0 = pk2(ca.x, ca.y), p1 = pk2(ca.z, ca.w);
            const unsigned p2 = pk2(cb.x, cb.y), p3 = pk2(cb.z, cb.w);
            const bool lo = (g < 2);
            inf.u[0] = lo ? p0 : cdw0;
            inf.u[1] = lo ? p1 : 0u;
            inf.u[2] = lo ? p2 : 0u;
            inf.u[3] = lo ? p3 : 0u;

            // GEMM1: x^T = [W1^T|b1].in^T + s1
            const f32x4 x0 = MFMA(A1[0], inf.v, s1[0]);
            const f32x4 x1 = MFMA(A1[1], inf.v, s1[1]);

            // D->B in-register: own D regs ARE the B-frag under relabeled A2
            FragU xf;
            xf.u[0] = pk2(x0[0], x0[1]); xf.u[1] = pk2(x0[2], x0[3]);
            xf.u[2] = pk2(x1[0], x1[1]); xf.u[3] = pk2(x1[2], x1[3]);

            // GEMM2: ns1 = tanh([Wr1^T|br1].x^T)
            const f32x4 d0 = MFMA(A2[0], xf.v, z4);
            const f32x4 d1 = MFMA(A2[1], xf.v, z4);
            float n1a[4], n1b[4], qa[4], qb[4];
#pragma unroll
            for (int r = 0; r < 4; ++r) {
                n1a[r] = fast_tanh(d0[r]); n1b[r] = fast_tanh(d1[r]);
                qa[r] = n1a[r] * n1a[r];   qb[r] = n1b[r] * n1b[r];
                s1[0][r] = n1a[r];         s1[1][r] = n1b[r];
            }
            // handoff: lane-aligned packed B-frags (no transpose needed)
            FragU nf, qf;
            nf.u[0] = pk2(n1a[0], n1a[1]); nf.u[1] = pk2(n1a[2], n1a[3]);
            nf.u[2] = pk2(n1b[0], n1b[1]); nf.u[3] = pk2(n1b[2], n1b[3]);
            qf.u[0] = pk2(qa[0], qa[1]);   qf.u[1] = pk2(qa[2], qa[3]);
            qf.u[2] = pk2(qb[0], qb[1]);   qf.u[3] = pk2(qb[2], qb[3]);
            const int slot = t & (SLOTS - 1);
            *(uint4*)&ringN[slot][lane][0] = make_uint4(nf.u[0], nf.u[1], nf.u[2], nf.u[3]);
            *(uint4*)&ringQ[slot][lane][0] = make_uint4(qf.u[0], qf.u[1], qf.u[2], qf.u[3]);
        };

        // load macro 0
        float4 ca[4], cb[4], na[4], nb[4];
        if (ld) {
#pragma unroll
            for (int i = 0; i < 4; ++i) {
                ca[i] = *(const float4*)(sp + i * 16);
                cb[i] = *(const float4*)(sp + i * 16 + 4);
            }
        }
#pragma unroll 1
        for (int j = 0; j < 64; ++j) {
            const int jn = (j + 1 < 64) ? j + 1 : j;     // prefetch next macro
            if (ld) {
#pragma unroll
                for (int i = 0; i < 4; ++i) {
                    na[i] = *(const float4*)(sp + (4 * jn + i) * 16);
                    nb[i] = *(const float4*)(sp + (4 * jn + i) * 16 + 4);
                }
            }
#pragma unroll
            for (int i = 0; i < 4; ++i) pstep(4 * j + i, ca[i], cb[i]);
            bar_sync();                                   // 64 in-loop barriers
#pragma unroll
            for (int i = 0; i < 4; ++i) { ca[i] = na[i]; cb[i] = nb[i]; }
        }
        bar_sync();                                       // barrier #65
    } else {
        // ================= CONSUMER: layer 2 (s2 chain) =================
        // A3a[t<3] = gamma-folded W2^T (relabeled rows); A3a[3]/A3b3 = sum tiles.
        bf16x8 A3a[4], A3b3, A4[3][2];
#pragma unroll
        for (int t = 0; t < 3; ++t) {
            const int m = 16 * t + j15;
            FragU f3, f4a, f4b;
#pragma unroll
            for (int j = 0; j < 8; ++j) {
                const int u = (j < 4) ? 4 * g + j : 16 + 4 * g + (j - 4);  // relabeled unit
                f3.v[j] = (short)f2bf(u < U1 ? g1[u] * W2[u * U2 + m] : 0.f);
                f4a.v[j] = (short)f2bf(Wr2[u * U2 + m]);               // y-units 0..31
                float vb = 0.f;
                if (j < 4) vb = Wr2[(32 + 4 * g + j) * U2 + m];        // y-units 32..47
                else if (j == 4 && g == 0) vb = br2[m];                // bias at formal k=4
                f4b.v[j] = (short)f2bf(vb);
            }
            A3a[t] = f3.v; A4[t][0] = f4a.v; A4[t][1] = f4b.v;
        }
        {   // sum tiles: rows m%4==0 -> ones over n1 units; rows m%4==1 -> over n1^2
            FragU fa, fb;
#pragma unroll
            for (int j = 0; j < 8; ++j) {
                const int u = (j < 4) ? 4 * g + j : 16 + 4 * g + (j - 4);
                fa.v[j] = ((j15 & 3) == 0 && u < U1) ? (short)0x3F80 : (short)0;
                fb.v[j] = ((j15 & 3) == 1 && u < U1) ? (short)0x3F80 : (short)0;
            }
            A3a[3] = fa.v; A3b3 = fb.v;
        }
        // per-lane LN-fold constants: c[m] = sum_k bf16(g1.W2), d[m] = b2 + W2^T.be1
        float cC[12], dC[12];
#pragma unroll
        for (int i = 0; i < 12; ++i) {
            const int m = 16 * (i >> 2) + 4 * g + (i & 3);
            float cc = 0.f, dd = b2[m];
            for (int k = 0; k < U1; ++k) {
                const float wq = bfr(g1[k] * W2[k * U2 + m]);   // match matmul quantization
                cc += wq;
                dd += be1[k] * W2[k * U2 + m];
            }
            cC[i] = cc; dC[i] = dd;
        }
        f32x4 s2[3] = {z4, z4, z4};

        auto cstep = [&](int t) {
            const int slot = t & (SLOTS - 1);
            const bf16x8 hf0 = *(const bf16x8*)&ringN[slot][lane][0];  // n1 frag
            const bf16x8 hf1 = *(const bf16x8*)&ringQ[slot][lane][0];  // n1^2 frag

            // sums first (gates rs), then P tiles — all off the s2 recurrence
            f32x4 sAcc = MFMA(A3a[3], hf0, z4);
            sAcc = MFMA(A3b3, hf1, sAcc);                 // reg0 = Sum n1, reg1 = Sum n1^2
            const f32x4 P0 = MFMA(A3a[0], hf0, z4);
            const f32x4 P1 = MFMA(A3a[1], hf0, z4);
            const f32x4 P2 = MFMA(A3a[2], hf0, z4);

            const float mu = sAcc[0] * (1.f / U1);
            const float var = sAcc[1] * (1.f / U1) - mu * mu;
            const float rs = hrsq(var + 1e-3f);

            // y = rs*(P - mu*c) + (d + s2)
            float y[12];
#pragma unroll
            for (int r = 0; r < 4; ++r) {
                y[r]     = fmaf(rs, fmaf(-mu, cC[r],     P0[r]), dC[r]     + s2[0][r]);
                y[4 + r] = fmaf(rs, fmaf(-mu, cC[4 + r], P1[r]), dC[4 + r] + s2[1][r]);
                y[8 + r] = fmaf(rs, fmaf(-mu, cC[8 + r], P2[r]), dC[8 + r] + s2[2][r]);
            }

            // y as B-frags in-register; bias 1.0 at formal (g==0, j==4) of yf1
            FragU yf0, yf1;
            yf0.u[0] = pk2(y[0], y[1]);  yf0.u[1] = pk2(y[2], y[3]);
            yf0.u[2] = pk2(y[4], y[5]);  yf0.u[3] = pk2(y[6], y[7]);
            yf1.u[0] = pk2(y[8], y[9]);  yf1.u[1] = pk2(y[10], y[11]);
            yf1.u[2] = (g == 0) ? 0x00003F80u : 0u;
            yf1.u[3] = 0u;

            // GEMM4: s2 = tanh([Wr2^T|br2].y^T)
#pragma unroll
            for (int t3 = 0; t3 < 3; ++t3) {
                f32x4 e = MFMA(A4[t3][0], yf0.v, z4);
                e = MFMA(A4[t3][1], yf1.v, e);
#pragma unroll
                for (int r = 0; r < 4; ++r) s2[t3][r] = fast_tanh(e[r]);
            }
        };

        bar_sync();                                       // wait for producer macro 0
#pragma unroll 1
        for (int j = 0; j < 64; ++j) {
#pragma unroll
            for (int i = 0; i < 4; ++i) cstep(4 * j + i);
            bar_sync();                                   // 64 in-loop barriers
        }

        // ---- epilogue: out = sigmoid(LN(s2) @ Wout + bout) ----
        float g2r[12], be2r[12], wor[12];
#pragma unroll
        for (int r = 0; r < 12; ++r) {
            const int n = 16 * (r >> 2) + 4 * g + (r & 3);
            g2r[r] = g2[n]; be2r[r] = be2[n]; wor[r] = Wout[n];
        }
        float sm = 0.f, sq = 0.f;
#pragma unroll
        for (int tt = 0; tt < 3; ++tt)
#pragma unroll
            for (int r = 0; r < 4; ++r) { const float v = s2[tt][r]; sm += v; sq += v * v; }
        sm += __shfl_xor(sm, 16, 64); sq += __shfl_xor(sq, 16, 64);
        sm += __shfl_xor(sm, 32, 64); sq += __shfl_xor(sq, 32, 64);
        const float mu = sm * (1.f / U2);
        const float var = sq * (1.f / U2) - mu * mu;
        const float rs = hrsq(var + 1e-3f);
        float p = 0.f;
#pragma unroll
        for (int tt = 0; tt < 3; ++tt)
#pragma unroll
            for (int r = 0; r < 4; ++r)
                p += ((s2[tt][r] - mu) * rs * g2r[4 * tt + r] + be2r[4 * tt + r]) * wor[4 * tt + r];
        p += __shfl_xor(p, 16, 64);
        p += __shfl_xor(p, 32, 64);
        if (lane < 16) {
            const float z = p + bout[0];
            // sigmoid via exp2 + HW rcp (once per output; keep cheap anyway)
            const float e = hexp2(-z * 1.4426950408889634f);
            out[blockIdx.x * 16 + lane] = hrcp(1.0f + e);
        }
    }
}

extern "C" void kernel_launch(void* const* d_in, const int* in_sizes, int n_in,
                              void* d_out, int out_size, void* d_ws, size_t ws_size,
                              hipStream_t stream) {
    const float* seq  = (const float*)d_in[0];
    const float* W1   = (const float*)d_in[1];
    const float* b1   = (const float*)d_in[2];
    const float* Wr1  = (const float*)d_in[3];
    const float* br1  = (const float*)d_in[4];
    const float* g1   = (const float*)d_in[5];
    const float* be1  = (const float*)d_in[6];
    const float* W2   = (const float*)d_in[7];
    const float* b2   = (const float*)d_in[8];
    const float* Wr2  = (const float*)d_in[9];
    const float* br2  = (const float*)d_in[10];
    const float* g2   = (const float*)d_in[11];
    const float* be2  = (const float*)d_in[12];
    const float* Wout = (const float*)d_in[13];
    const float* bout = (const float*)d_in[14];
    float* out = (float*)d_out;

    const int B = in_sizes[0] / (T_STEPS * FEAT);   // 8192
    const int grid = B / 16;                        // 512 blocks x 2 waves
    rnn_kernel<<<grid, 128, 0, stream>>>(seq, W1, b1, Wr1, br1, g1, be1,
                                         W2, b2, Wr2, br2, g2, be2, Wout, bout, out);
}